// Round 19
// baseline (239.182 us; speedup 1.0000x reference)
//
#include <hip/hip_runtime.h>

#define HW 16384
#define C_IN 256
#define C_MID 128
#define C_OUT 32
#define EPSF 1e-5f

typedef __bf16 bf16x8 __attribute__((ext_vector_type(8)));
typedef __bf16 bf16x4 __attribute__((ext_vector_type(4)));
typedef float f32x4 __attribute__((ext_vector_type(4)));

__device__ __forceinline__ bf16x4 cvt4(f32x4 v) {
    bf16x4 r;
    r[0] = (__bf16)v[0]; r[1] = (__bf16)v[1];
    r[2] = (__bf16)v[2]; r[3] = (__bf16)v[3];
    return r;
}

// ---------------- Kernel 1a: style stats + bf16 copy ----------
__global__ __launch_bounds__(512) void k_stats_s(const float* __restrict__ style,
                                                 float* __restrict__ smean,
                                                 __bf16* __restrict__ sbf) {
    const int bc = blockIdx.x;
    const int t = threadIdx.x;
    const f32x4* sp = (const f32x4*)(style + (size_t)bc * HW);
    const int phase = (bc * 257) & 4095;

    int idx[8];
    #pragma unroll
    for (int i = 0; i < 8; ++i) idx[i] = (phase + t + i * 512) & 4095;

    f32x4 s[8];
    #pragma unroll
    for (int i = 0; i < 8; ++i) s[i] = __builtin_nontemporal_load(sp + idx[i]);
    asm volatile("" ::
        "v"(s[0]), "v"(s[1]), "v"(s[2]), "v"(s[3]),
        "v"(s[4]), "v"(s[5]), "v"(s[6]), "v"(s[7]));

    {
        bf16x4* sb = (bf16x4*)(sbf + (size_t)bc * HW);
        #pragma unroll
        for (int i = 0; i < 8; ++i) sb[idx[i]] = cvt4(s[i]);
    }

    f32x4 a01 = s[0] + s[1], a23 = s[2] + s[3], a45 = s[4] + s[5], a67 = s[6] + s[7];
    f32x4 a = (a01 + a23) + (a45 + a67);
    float ss = (a[0] + a[1]) + (a[2] + a[3]);

    #pragma unroll
    for (int d = 32; d > 0; d >>= 1) ss += __shfl_xor(ss, d, 64);
    __shared__ float rss[8];
    const int wv = t >> 6;
    if ((t & 63) == 0) rss[wv] = ss;
    __syncthreads();
    if (t == 0) {
        float S = 0.f;
        #pragma unroll
        for (int i = 0; i < 8; ++i) S += rss[i];
        smean[bc] = S / (float)HW;
    }
}

// ---------------- Kernel 1b: content stats + bf16 copy (chunk-sliced) -------
__global__ __launch_bounds__(512) void k_stats_c(const float* __restrict__ content,
                                                 float* __restrict__ cmean,
                                                 float* __restrict__ crstd,
                                                 __bf16* __restrict__ cbf) {
    const int bc = blockIdx.x;
    const int t = threadIdx.x;
    const f32x4* cp = (const f32x4*)(content + (size_t)bc * HW);
    const int phase = (bc * 257) & 4095;

    int idx[8];
    #pragma unroll
    for (int i = 0; i < 8; ++i) idx[i] = (phase + t + i * 512) & 4095;

    f32x4 c[8];
    #pragma unroll
    for (int i = 0; i < 8; ++i) c[i] = __builtin_nontemporal_load(cp + idx[i]);
    asm volatile("" ::
        "v"(c[0]), "v"(c[1]), "v"(c[2]), "v"(c[3]),
        "v"(c[4]), "v"(c[5]), "v"(c[6]), "v"(c[7]));

    {
        bf16x4* cb = (bf16x4*)(cbf + (size_t)bc * HW);
        #pragma unroll
        for (int i = 0; i < 8; ++i) cb[idx[i]] = cvt4(c[i]);
    }

    f32x4 a01 = c[0] + c[1], a23 = c[2] + c[3], a45 = c[4] + c[5], a67 = c[6] + c[7];
    f32x4 a = (a01 + a23) + (a45 + a67);
    float cs = (a[0] + a[1]) + (a[2] + a[3]);
    f32x4 q01 = c[0]*c[0] + c[1]*c[1], q23 = c[2]*c[2] + c[3]*c[3];
    f32x4 q45 = c[4]*c[4] + c[5]*c[5], q67 = c[6]*c[6] + c[7]*c[7];
    f32x4 q = (q01 + q23) + (q45 + q67);
    float cq = (q[0] + q[1]) + (q[2] + q[3]);

    #pragma unroll
    for (int d = 32; d > 0; d >>= 1) {
        cs += __shfl_xor(cs, d, 64);
        cq += __shfl_xor(cq, d, 64);
    }
    __shared__ float rs[8], rq[8];
    const int wv = t >> 6;
    if ((t & 63) == 0) { rs[wv] = cs; rq[wv] = cq; }
    __syncthreads();
    if (t == 0) {
        float S = 0.f, Q = 0.f;
        #pragma unroll
        for (int i = 0; i < 8; ++i) { S += rs[i]; Q += rq[i]; }
        float n = (float)HW;
        float var = (Q - S * S / n) / (n - 1.f);
        cmean[bc] = S / n;
        crstd[bc] = 1.f / sqrtf(var + EPSF);
    }
}

// ---------------- Prep (style half): W1s, bias1s, W2b ----------
__global__ __launch_bounds__(256) void k_wprep_s(const float* __restrict__ w1,
                                                 const float* __restrict__ b1,
                                                 const float* __restrict__ w2,
                                                 const float* __restrict__ smean,
                                                 __bf16* __restrict__ W1s,
                                                 float* __restrict__ bias1s,
                                                 __bf16* __restrict__ W2b) {
    int o = blockIdx.x, b = blockIdx.y, t = threadIdx.x;
    float w = w1[o * 256 + t];
    if (b == 0) {
        W1s[o * 256 + t] = (__bf16)w;
        if (t < 32) W2b[o * 32 + t] = (__bf16)w2[o * 32 + t];
    }
    float ps = w * smean[b * 256 + t];
    __shared__ float rB[256];
    rB[t] = ps;
    __syncthreads();
    for (int off = 128; off > 0; off >>= 1) {
        if (t < off) rB[t] += rB[t + off];
        __syncthreads();
    }
    if (t == 0) bias1s[b * 128 + o] = b1[o] - rB[0];
}

// ---------------- Prep (content half, chunk-sliced): W1c, bias1c ----------
__global__ __launch_bounds__(256) void k_wprep_c(const float* __restrict__ w1,
                                                 const float* __restrict__ b1,
                                                 const float* __restrict__ cmean,
                                                 const float* __restrict__ crstd,
                                                 __bf16* __restrict__ W1c,
                                                 float* __restrict__ bias1c) {
    int o = blockIdx.x, b = blockIdx.y, t = threadIdx.x;
    float w = w1[o * 256 + t];
    float r = crstd[b * 256 + t];
    float wc = w * r;
    W1c[((size_t)(b * 128 + o)) * 256 + t] = (__bf16)wc;
    float pc = wc * cmean[b * 256 + t];
    __shared__ float rA[256];
    rA[t] = pc;
    __syncthreads();
    for (int off = 128; off > 0; off >>= 1) {
        if (t < off) rA[t] += rA[t + off];
        __syncthreads();
    }
    if (t == 0) bias1c[b * 128 + o] = b1[o] - rA[0];
}

// Vectorized staging (full 256-channel tile), used by k_net_s.
__device__ __forceinline__ void stage_tile(const __bf16* __restrict__ xb,
                                           int p0, int tid, __bf16* Xl) {
    const int c = tid;
    const __bf16* src = xb + (size_t)c * HW + p0;
    bf16x8 v[8];
    #pragma unroll
    for (int j = 0; j < 8; ++j) v[j] = *(const bf16x8*)(src + j * 8);
    char* base = (char*)Xl;
    #pragma unroll
    for (int j = 0; j < 8; ++j) {
        #pragma unroll
        for (int e = 0; e < 8; ++e)
            *(__bf16*)(base + (j * 8 + e) * 512 + ((2 * c) ^ (e << 4))) = v[j][e];
    }
}

// ---------------- Kernel 2: MFMA fused net (style) + partial gram ----------
__global__ __launch_bounds__(256) void k_net_s(const __bf16* __restrict__ x,
                                               const __bf16* __restrict__ W1,
                                               const float* __restrict__ bias1,
                                               const __bf16* __restrict__ W2,
                                               const float* __restrict__ b2,
                                               float* __restrict__ partial) {
    __shared__ __bf16 Xl[64 * 256];
    __shared__ __bf16 Tl[64 * 128];
    const int tid = threadIdx.x;
    const int l = tid & 63, wv = tid >> 6;
    const int lr = l & 15, g = l >> 4;
    const int sw = (lr & 7) << 4;
    const int p0 = blockIdx.x * 64;
    const int b = blockIdx.y;
    const __bf16* xb = x + (size_t)b * C_IN * HW;

    stage_tile(xb, p0, tid, Xl);
    __syncthreads();

    const f32x4 zero4 = {0.f, 0.f, 0.f, 0.f};
    f32x4 acc[2][4];
    #pragma unroll
    for (int mt = 0; mt < 2; ++mt)
        #pragma unroll
        for (int nt = 0; nt < 4; ++nt) acc[mt][nt] = zero4;

    const __bf16* wrow0 = W1 + (size_t)(wv * 32 + lr) * 256 + g * 8;
    const __bf16* wrow1 = wrow0 + 16 * 256;

    #pragma unroll
    for (int kt = 0; kt < 8; ++kt) {
        bf16x8 a0 = *(const bf16x8*)(wrow0 + kt * 32);
        bf16x8 a1 = *(const bf16x8*)(wrow1 + kt * 32);
        #pragma unroll
        for (int nt = 0; nt < 4; ++nt) {
            const char* xrow = (const char*)&Xl[(nt * 16 + lr) * 256];
            bf16x8 bfr = *(const bf16x8*)(xrow + (((kt * 32 + g * 8) * 2) ^ sw));
            acc[0][nt] = __builtin_amdgcn_mfma_f32_16x16x32_bf16(a0, bfr, acc[0][nt], 0, 0, 0);
            acc[1][nt] = __builtin_amdgcn_mfma_f32_16x16x32_bf16(a1, bfr, acc[1][nt], 0, 0, 0);
        }
    }

    float4 bia[2];
    bia[0] = *(const float4*)&bias1[b * 128 + wv * 32 + g * 4];
    bia[1] = *(const float4*)&bias1[b * 128 + wv * 32 + 16 + g * 4];
    __syncthreads();
    #pragma unroll
    for (int mt = 0; mt < 2; ++mt) {
        #pragma unroll
        for (int nt = 0; nt < 4; ++nt) {
            const int p = nt * 16 + lr;
            char* trow = (char*)&Tl[p * 128];
            const int ob = (wv * 32 + mt * 16 + g * 4) * 2;
            bf16x4 tv;
            tv[0] = (__bf16)fmaxf(acc[mt][nt][0] + bia[mt].x, 0.f);
            tv[1] = (__bf16)fmaxf(acc[mt][nt][1] + bia[mt].y, 0.f);
            tv[2] = (__bf16)fmaxf(acc[mt][nt][2] + bia[mt].z, 0.f);
            tv[3] = (__bf16)fmaxf(acc[mt][nt][3] + bia[mt].w, 0.f);
            *(bf16x4*)(trow + (ob ^ sw)) = tv;
        }
    }
    __syncthreads();

    f32x4 acc2[2];
    acc2[0] = zero4; acc2[1] = zero4;
    const int p = wv * 16 + lr;
    const char* trow = (const char*)&Tl[p * 128];
    const __bf16* w2r0 = W2 + (size_t)lr * 128 + g * 8;
    const __bf16* w2r1 = w2r0 + 16 * 128;
    #pragma unroll
    for (int kt = 0; kt < 4; ++kt) {
        bf16x8 bfr = *(const bf16x8*)(trow + (((kt * 32 + g * 8) * 2) ^ sw));
        bf16x8 a0 = *(const bf16x8*)(w2r0 + kt * 32);
        bf16x8 a1 = *(const bf16x8*)(w2r1 + kt * 32);
        acc2[0] = __builtin_amdgcn_mfma_f32_16x16x32_bf16(a0, bfr, acc2[0], 0, 0, 0);
        acc2[1] = __builtin_amdgcn_mfma_f32_16x16x32_bf16(a1, bfr, acc2[1], 0, 0, 0);
    }
    float4 bb0 = *(const float4*)&b2[g * 4];
    float4 bb1 = *(const float4*)&b2[16 + g * 4];
    const int o0 = g * 4;

    float* gt = (float*)Xl;
    gt[(o0 + 0) * 65 + p] = acc2[0][0] + bb0.x;
    gt[(o0 + 1) * 65 + p] = acc2[0][1] + bb0.y;
    gt[(o0 + 2) * 65 + p] = acc2[0][2] + bb0.z;
    gt[(o0 + 3) * 65 + p] = acc2[0][3] + bb0.w;
    gt[(16 + o0 + 0) * 65 + p] = acc2[1][0] + bb1.x;
    gt[(16 + o0 + 1) * 65 + p] = acc2[1][1] + bb1.y;
    gt[(16 + o0 + 2) * 65 + p] = acc2[1][2] + bb1.z;
    gt[(16 + o0 + 3) * 65 + p] = acc2[1][3] + bb1.w;
    __syncthreads();
    const int gi = tid >> 3, jb = (tid & 7) * 4;
    float g4[4] = {0.f, 0.f, 0.f, 0.f};
    #pragma unroll 8
    for (int n = 0; n < 64; ++n) {
        float si = gt[gi * 65 + n];
        #pragma unroll
        for (int q = 0; q < 4; ++q)
            g4[q] = fmaf(si, gt[(jb + q) * 65 + n], g4[q]);
    }
    float* dst = partial + ((size_t)(b * 256 + blockIdx.x)) * 1024 + tid * 4;
    #pragma unroll
    for (int q = 0; q < 4; ++q) dst[q] = g4[q];
}

// ---------------- Kernel 3: reduce 256 partials + softmax + scale ----------
__global__ __launch_bounds__(1024) void k_softmax2(const float* __restrict__ partial,
                                                   float* __restrict__ scov) {
    int b = blockIdx.x;
    int j = threadIdx.x, i = threadIdx.y;
    const float* base = partial + (size_t)b * 256 * 1024 + i * 32 + j;
    float v0 = 0.f, v1 = 0.f, v2 = 0.f, v3 = 0.f;
    #pragma unroll 4
    for (int s = 0; s < 256; s += 4) {
        v0 += base[(s + 0) * 1024];
        v1 += base[(s + 1) * 1024];
        v2 += base[(s + 2) * 1024];
        v3 += base[(s + 3) * 1024];
    }
    float v = ((v0 + v1) + (v2 + v3)) * (1.f / (float)HW);
    float m = v;
    #pragma unroll
    for (int d = 16; d > 0; d >>= 1) m = fmaxf(m, __shfl_xor(m, d, 32));
    float e = expf(v - m);
    float sum = e;
    #pragma unroll
    for (int d = 16; d > 0; d >>= 1) sum += __shfl_xor(sum, d, 32);
    scov[(size_t)b * 1024 + i * 32 + j] = e / sum * 0.17677669529663687f;
}

// ---------------- Kernel 4: FUSED net(content) + g=scov@cF + up-conv + out --
// r18 structure (dbuf chunks, 44 KB LDS, 3 blk/CU); chunk-sliced launches.
__global__ __launch_bounds__(256, 3) void k_netc_final(const __bf16* __restrict__ x,
                                                       const __bf16* __restrict__ W1,
                                                       const float* __restrict__ bias1,
                                                       const __bf16* __restrict__ W2,
                                                       const float* __restrict__ b2,
                                                       const float* __restrict__ scov,
                                                       const float* __restrict__ wu,
                                                       const float* __restrict__ bu,
                                                       const float* __restrict__ smean,
                                                       float* __restrict__ out) {
    __shared__ char smem[45056];
    __bf16* Xb[2] = {(__bf16*)smem, (__bf16*)(smem + 8192)};
    __bf16* Tl  = (__bf16*)(smem + 16384);
    float* sCov = (float*)(smem + 32768);
    float* sG   = (float*)(smem + 36864);
    float* sC   = (float*)(smem + 16384);

    const int tid = threadIdx.x;
    const int l = tid & 63, wv = tid >> 6;
    const int lr = l & 15, g = l >> 4;
    const int sw = (lr & 7) << 4;
    const int p0 = blockIdx.x * 64;
    const int b = blockIdx.y;
    const __bf16* xb = x + (size_t)b * C_IN * HW;

    const int cl = tid & 63;
    const int pq = (tid >> 6) * 16;

    #pragma unroll
    for (int q = 0; q < 4; ++q)
        sCov[tid + 256 * q] = scov[(size_t)b * 1024 + tid + 256 * q];

    bf16x8 stg0, stg1;
    {
        const __bf16* src = xb + (size_t)cl * HW + p0 + pq;
        stg0 = *(const bf16x8*)src;
        stg1 = *(const bf16x8*)(src + 8);
        char* base = (char*)Xb[0];
        #pragma unroll
        for (int e = 0; e < 8; ++e) {
            int p = pq + e;
            *(__bf16*)(base + p * 128 + ((2 * cl) ^ ((p & 7) << 4))) = stg0[e];
        }
        #pragma unroll
        for (int e = 0; e < 8; ++e) {
            int p = pq + 8 + e;
            *(__bf16*)(base + p * 128 + ((2 * cl) ^ ((p & 7) << 4))) = stg1[e];
        }
    }
    __syncthreads();

    const f32x4 zero4 = {0.f, 0.f, 0.f, 0.f};
    f32x4 acc1[2][4];
    #pragma unroll
    for (int mt = 0; mt < 2; ++mt)
        #pragma unroll
        for (int nt = 0; nt < 4; ++nt) acc1[mt][nt] = zero4;

    const __bf16* W1b = W1 + ((size_t)b << 15);
    const __bf16* wbase = W1b + (size_t)(wv * 32 + lr) * 256 + g * 8;

    #pragma unroll
    for (int kc = 0; kc < 4; ++kc) {
        const __bf16* cur = Xb[kc & 1];
        if (kc < 3) {
            const __bf16* src = xb + (size_t)((kc + 1) * 64 + cl) * HW + p0 + pq;
            stg0 = *(const bf16x8*)src;
            stg1 = *(const bf16x8*)(src + 8);
        }
        #pragma unroll
        for (int kt = 0; kt < 2; ++kt) {
            const __bf16* w0 = wbase + kc * 64 + kt * 32;
            bf16x8 a0 = *(const bf16x8*)w0;
            bf16x8 a1 = *(const bf16x8*)(w0 + 16 * 256);
            #pragma unroll
            for (int nt = 0; nt < 4; ++nt) {
                const char* xrow = (const char*)cur + (nt * 16 + lr) * 128;
                bf16x8 bfr = *(const bf16x8*)(xrow + (((kt * 32 + g * 8) * 2) ^ sw));
                acc1[0][nt] = __builtin_amdgcn_mfma_f32_16x16x32_bf16(a0, bfr, acc1[0][nt], 0, 0, 0);
                acc1[1][nt] = __builtin_amdgcn_mfma_f32_16x16x32_bf16(a1, bfr, acc1[1][nt], 0, 0, 0);
            }
        }
        if (kc < 3) {
            char* base = (char*)Xb[(kc + 1) & 1];
            #pragma unroll
            for (int e = 0; e < 8; ++e) {
                int p = pq + e;
                *(__bf16*)(base + p * 128 + ((2 * cl) ^ ((p & 7) << 4))) = stg0[e];
            }
            #pragma unroll
            for (int e = 0; e < 8; ++e) {
                int p = pq + 8 + e;
                *(__bf16*)(base + p * 128 + ((2 * cl) ^ ((p & 7) << 4))) = stg1[e];
            }
            __syncthreads();
        }
    }

    float4 bia[2];
    bia[0] = *(const float4*)&bias1[b * 128 + wv * 32 + g * 4];
    bia[1] = *(const float4*)&bias1[b * 128 + wv * 32 + 16 + g * 4];
    #pragma unroll
    for (int mt = 0; mt < 2; ++mt) {
        #pragma unroll
        for (int nt = 0; nt < 4; ++nt) {
            const int p = nt * 16 + lr;
            char* trow = (char*)&Tl[p * 128];
            const int ob = (wv * 32 + mt * 16 + g * 4) * 2;
            bf16x4 tv;
            tv[0] = (__bf16)fmaxf(acc1[mt][nt][0] + bia[mt].x, 0.f);
            tv[1] = (__bf16)fmaxf(acc1[mt][nt][1] + bia[mt].y, 0.f);
            tv[2] = (__bf16)fmaxf(acc1[mt][nt][2] + bia[mt].z, 0.f);
            tv[3] = (__bf16)fmaxf(acc1[mt][nt][3] + bia[mt].w, 0.f);
            *(bf16x4*)(trow + (ob ^ sw)) = tv;
        }
    }
    __syncthreads();

    f32x4 acc2[2];
    acc2[0] = zero4; acc2[1] = zero4;
    const int p = wv * 16 + lr;
    {
        const char* trow = (const char*)&Tl[p * 128];
        const __bf16* w2r0 = W2 + (size_t)lr * 128 + g * 8;
        const __bf16* w2r1 = w2r0 + 16 * 128;
        #pragma unroll
        for (int kt = 0; kt < 4; ++kt) {
            bf16x8 bfr = *(const bf16x8*)(trow + (((kt * 32 + g * 8) * 2) ^ sw));
            bf16x8 a0 = *(const bf16x8*)(w2r0 + kt * 32);
            bf16x8 a1 = *(const bf16x8*)(w2r1 + kt * 32);
            acc2[0] = __builtin_amdgcn_mfma_f32_16x16x32_bf16(a0, bfr, acc2[0], 0, 0, 0);
            acc2[1] = __builtin_amdgcn_mfma_f32_16x16x32_bf16(a1, bfr, acc2[1], 0, 0, 0);
        }
    }
    float4 bb0 = *(const float4*)&b2[g * 4];
    float4 bb1 = *(const float4*)&b2[16 + g * 4];
    const int o0 = g * 4;

    __syncthreads();
    sC[(o0 + 0) * 64 + p] = acc2[0][0] + bb0.x;
    sC[(o0 + 1) * 64 + p] = acc2[0][1] + bb0.y;
    sC[(o0 + 2) * 64 + p] = acc2[0][2] + bb0.z;
    sC[(o0 + 3) * 64 + p] = acc2[0][3] + bb0.w;
    sC[(16 + o0 + 0) * 64 + p] = acc2[1][0] + bb1.x;
    sC[(16 + o0 + 1) * 64 + p] = acc2[1][1] + bb1.y;
    sC[(16 + o0 + 2) * 64 + p] = acc2[1][2] + bb1.z;
    sC[(16 + o0 + 3) * 64 + p] = acc2[1][3] + bb1.w;
    __syncthreads();

    {
        int gp = tid & 63, gib = (tid >> 6) * 8;
        #pragma unroll
        for (int rr = 0; rr < 8; ++rr) {
            int gi = gib + rr;
            float a = 0.f;
            #pragma unroll
            for (int k = 0; k < 32; ++k)
                a = fmaf(sCov[gi * 32 + k], sC[k * 64 + gp], a);
            sG[gi * 64 + gp] = a;
        }
    }
    __syncthreads();

    const int tx = tid & 7, ty = tid >> 3;
    const float* wurow = wu + (size_t)(ty * 8) * 32;
    float acc[8][8];
    #pragma unroll
    for (int i = 0; i < 8; ++i)
        #pragma unroll
        for (int j = 0; j < 8; ++j) acc[i][j] = 0.f;
    #pragma unroll 4
    for (int k = 0; k < 32; ++k) {
        float a[8];
        #pragma unroll
        for (int i = 0; i < 8; ++i) a[i] = wurow[i * 32 + k];
        float4 b4a = *(const float4*)&sG[k * 64 + tx * 8];
        float4 b4b = *(const float4*)&sG[k * 64 + tx * 8 + 4];
        float bb[8] = {b4a.x, b4a.y, b4a.z, b4a.w, b4b.x, b4b.y, b4b.z, b4b.w};
        #pragma unroll
        for (int i = 0; i < 8; ++i)
            #pragma unroll
            for (int j = 0; j < 8; ++j)
                acc[i][j] = fmaf(a[i], bb[j], acc[i][j]);
    }
    #pragma unroll
    for (int i = 0; i < 8; ++i) {
        int o = ty * 8 + i;
        float add = bu[o] + smean[b * 256 + o];
        const __bf16* csrc = xb + (size_t)o * HW + p0 + tx * 8;
        bf16x8 rv = *(const bf16x8*)csrc;
        float* dst = out + (size_t)b * C_IN * HW + (size_t)o * HW + p0 + tx * 8;
        f32x4 r0 = {acc[i][0] + add + (float)rv[0], acc[i][1] + add + (float)rv[1],
                    acc[i][2] + add + (float)rv[2], acc[i][3] + add + (float)rv[3]};
        f32x4 r1 = {acc[i][4] + add + (float)rv[4], acc[i][5] + add + (float)rv[5],
                    acc[i][6] + add + (float)rv[6], acc[i][7] + add + (float)rv[7]};
        __builtin_nontemporal_store(r0, (f32x4*)dst);
        __builtin_nontemporal_store(r1, (f32x4*)(dst + 4));
    }
}

extern "C" void kernel_launch(void* const* d_in, const int* in_sizes, int n_in,
                              void* d_out, int out_size, void* d_ws, size_t ws_size,
                              hipStream_t stream) {
    const float* content = (const float*)d_in[0];
    const float* style   = (const float*)d_in[1];
    const float* w1      = (const float*)d_in[2];
    const float* b1      = (const float*)d_in[3];
    const float* w2      = (const float*)d_in[4];
    const float* b2      = (const float*)d_in[5];
    const float* wu      = (const float*)d_in[6];
    const float* bu      = (const float*)d_in[7];
    float* out = (float*)d_out;
    float* ws  = (float*)d_ws;

    float* cmean   = ws;                       // 2048
    float* crstd   = ws + 2048;                // 2048
    float* smean   = ws + 4096;                // 2048
    float* scov    = ws + 6144;                // 8192
    float* bias1c  = ws + 14336;               // 1024
    float* bias1s  = ws + 15360;               // 1024
    __bf16* W2b    = (__bf16*)(ws + 16384);    // 4096 bf16
    __bf16* W1s    = (__bf16*)(ws + 18432);    // 32768 bf16
    __bf16* W1c    = (__bf16*)(ws + 34816);    // 262144 bf16
    float* partial = ws + 165888;              // 2097152 (8 MB)
    __bf16* cbf    = (__bf16*)(ws + 2263040);  // 33554432 bf16 (67 MB)
    __bf16* sbf    = (__bf16*)(ws + 19040256); // 33554432 bf16 (67 MB)

    // ---- style side (whole) ----
    k_stats_s<<<dim3(2048), 512, 0, stream>>>(style, smean, sbf);
    k_wprep_s<<<dim3(128, 8), 256, 0, stream>>>(w1, b1, w2, smean, W1s, bias1s, W2b);
    k_net_s<<<dim3(256, 8), 256, 0, stream>>>(sbf, W1s, bias1s, W2b, b2, partial);
    k_softmax2<<<dim3(8), dim3(32, 32), 0, stream>>>(partial, scov);

    // ---- content side: 2 chunks of 4 batches; cbf chunk consumed while L3-hot
    const int CB = 4;                             // batches per chunk
    const size_t PL = (size_t)CB * C_IN * HW;     // elements per chunk (plane data)
    for (int c = 0; c < 2; ++c) {
        const float* cc   = content + (size_t)c * PL;
        __bf16* cbfc      = cbf + (size_t)c * PL;
        float* cmeanc     = cmean + c * CB * 256;
        float* crstdc     = crstd + c * CB * 256;
        __bf16* W1cc      = W1c + (size_t)c * CB * 128 * 256;
        float* bias1cc    = bias1c + c * CB * 128;
        const float* scovc  = scov + c * CB * 1024;
        const float* smeanc = smean + c * CB * 256;
        float* outc       = out + (size_t)c * PL;

        k_stats_c<<<dim3(CB * 256), 512, 0, stream>>>(cc, cmeanc, crstdc, cbfc);
        k_wprep_c<<<dim3(128, CB), 256, 0, stream>>>(w1, b1, cmeanc, crstdc, W1cc, bias1cc);
        k_netc_final<<<dim3(256, CB), 256, 0, stream>>>(cbfc, W1cc, bias1cc, W2b, b2,
                                                        scovc, wu, bu, smeanc, outc);
    }
}

// Round 20
// 222.030 us; speedup vs baseline: 1.0772x; 1.0772x over previous
//
#include <hip/hip_runtime.h>

#define HW 16384
#define C_IN 256
#define C_MID 128
#define C_OUT 32
#define EPSF 1e-5f

typedef __bf16 bf16x8 __attribute__((ext_vector_type(8)));
typedef __bf16 bf16x4 __attribute__((ext_vector_type(4)));
typedef float f32x4 __attribute__((ext_vector_type(4)));

__device__ __forceinline__ bf16x4 cvt4(f32x4 v) {
    bf16x4 r;
    r[0] = (__bf16)v[0]; r[1] = (__bf16)v[1];
    r[2] = (__bf16)v[2]; r[3] = (__bf16)v[3];
    return r;
}

// ---------------- Kernel 1: stats + bf16 copies of both inputs ----------
__global__ __launch_bounds__(512) void k_stats10(const float* __restrict__ content,
                                                 const float* __restrict__ style,
                                                 float* __restrict__ cmean,
                                                 float* __restrict__ crstd,
                                                 float* __restrict__ smean,
                                                 __bf16* __restrict__ cbf,
                                                 __bf16* __restrict__ sbf) {
    const int bc = blockIdx.x;          // 0..2047
    const int t = threadIdx.x;          // 0..511
    const f32x4* cp = (const f32x4*)(content + (size_t)bc * HW);
    const f32x4* sp = (const f32x4*)(style + (size_t)bc * HW);
    const int phase = (bc * 257) & 4095;

    int idx[8];
    #pragma unroll
    for (int i = 0; i < 8; ++i) idx[i] = (phase + t + i * 512) & 4095;

    f32x4 c[8], s[8];
    #pragma unroll
    for (int i = 0; i < 8; ++i) c[i] = __builtin_nontemporal_load(cp + idx[i]);
    #pragma unroll
    for (int i = 0; i < 8; ++i) s[i] = __builtin_nontemporal_load(sp + idx[i]);
    asm volatile("" ::
        "v"(c[0]), "v"(c[1]), "v"(c[2]), "v"(c[3]), "v"(c[4]), "v"(c[5]), "v"(c[6]), "v"(c[7]),
        "v"(s[0]), "v"(s[1]), "v"(s[2]), "v"(s[3]), "v"(s[4]), "v"(s[5]), "v"(s[6]), "v"(s[7]));

    {
        bf16x4* cb = (bf16x4*)(cbf + (size_t)bc * HW);
        bf16x4* sb = (bf16x4*)(sbf + (size_t)bc * HW);
        #pragma unroll
        for (int i = 0; i < 8; ++i) {
            cb[idx[i]] = cvt4(c[i]);
            sb[idx[i]] = cvt4(s[i]);
        }
    }

    float cs, cq, ss;
    {
        f32x4 a01 = c[0] + c[1], a23 = c[2] + c[3], a45 = c[4] + c[5], a67 = c[6] + c[7];
        f32x4 a = (a01 + a23) + (a45 + a67);
        cs = (a[0] + a[1]) + (a[2] + a[3]);
        f32x4 q01 = c[0]*c[0] + c[1]*c[1], q23 = c[2]*c[2] + c[3]*c[3];
        f32x4 q45 = c[4]*c[4] + c[5]*c[5], q67 = c[6]*c[6] + c[7]*c[7];
        f32x4 q = (q01 + q23) + (q45 + q67);
        cq = (q[0] + q[1]) + (q[2] + q[3]);
        f32x4 b01 = s[0] + s[1], b23 = s[2] + s[3], b45 = s[4] + s[5], b67 = s[6] + s[7];
        f32x4 bsum = (b01 + b23) + (b45 + b67);
        ss = (bsum[0] + bsum[1]) + (bsum[2] + bsum[3]);
    }

    #pragma unroll
    for (int d = 32; d > 0; d >>= 1) {
        cs += __shfl_xor(cs, d, 64);
        cq += __shfl_xor(cq, d, 64);
        ss += __shfl_xor(ss, d, 64);
    }
    __shared__ float rs[8], rq[8], rss[8];
    const int wv = t >> 6;
    if ((t & 63) == 0) { rs[wv] = cs; rq[wv] = cq; rss[wv] = ss; }
    __syncthreads();
    if (t == 0) {
        float S = 0.f, Q = 0.f, SS = 0.f;
        #pragma unroll
        for (int i = 0; i < 8; ++i) { S += rs[i]; Q += rq[i]; SS += rss[i]; }
        float n = (float)HW;
        float var = (Q - S * S / n) / (n - 1.f);
        cmean[bc] = S / n;
        crstd[bc] = 1.f / sqrtf(var + EPSF);
        smean[bc] = SS / n;
    }
}

// ---------------- Prep: fold norm into conv1 weights + w2 convert ----------
__global__ __launch_bounds__(256) void k_wprep2(const float* __restrict__ w1,
                                                const float* __restrict__ b1,
                                                const float* __restrict__ w2,
                                                const float* __restrict__ cmean,
                                                const float* __restrict__ crstd,
                                                const float* __restrict__ smean,
                                                __bf16* __restrict__ W1c,
                                                float* __restrict__ bias1c,
                                                __bf16* __restrict__ W1s,
                                                float* __restrict__ bias1s,
                                                __bf16* __restrict__ W2b) {
    int o = blockIdx.x, b = blockIdx.y, t = threadIdx.x;
    float w = w1[o * 256 + t];
    float r = crstd[b * 256 + t];
    float wc = w * r;
    W1c[((size_t)(b * 128 + o)) * 256 + t] = (__bf16)wc;
    if (b == 0) {
        W1s[o * 256 + t] = (__bf16)w;
        if (t < 32) W2b[o * 32 + t] = (__bf16)w2[o * 32 + t];
    }
    float pc = wc * cmean[b * 256 + t];
    float ps = w * smean[b * 256 + t];
    __shared__ float rA[256], rB[256];
    rA[t] = pc; rB[t] = ps;
    __syncthreads();
    for (int off = 128; off > 0; off >>= 1) {
        if (t < off) { rA[t] += rA[t + off]; rB[t] += rB[t + off]; }
        __syncthreads();
    }
    if (t == 0) {
        bias1c[b * 128 + o] = b1[o] - rA[0];
        bias1s[b * 128 + o] = b1[o] - rB[0];
    }
}

// ---------------- Kernel 2: MFMA fused net (style) + partial gram ----------
__global__ __launch_bounds__(256) void k_net_s(const __bf16* __restrict__ x,
                                               const __bf16* __restrict__ W1,
                                               const float* __restrict__ bias1,
                                               const __bf16* __restrict__ W2,
                                               const float* __restrict__ b2,
                                               float* __restrict__ partial) {
    __shared__ __bf16 Xl[64 * 256];   // 32 KB; reused as f32 gram tile at end
    __shared__ __bf16 Tl[64 * 128];   // 16 KB
    const int tid = threadIdx.x;
    const int l = tid & 63, wv = tid >> 6;
    const int lr = l & 15, g = l >> 4;
    const int sw = (lr & 7) << 4;
    const int p0 = blockIdx.x * 64;
    const int b = blockIdx.y;
    const __bf16* xb = x + (size_t)b * C_IN * HW;

    {
        const int p = wv * 16 + lr;
        const __bf16* xp = xb + p0 + p;
        char* row = (char*)&Xl[p * 256];
        #pragma unroll 4
        for (int cc = 0; cc < 16; ++cc) {
            const int c = cc * 16 + g * 4;
            bf16x4 v;
            v[0] = xp[(size_t)(c + 0) * HW];
            v[1] = xp[(size_t)(c + 1) * HW];
            v[2] = xp[(size_t)(c + 2) * HW];
            v[3] = xp[(size_t)(c + 3) * HW];
            *(bf16x4*)(row + ((c * 2) ^ sw)) = v;
        }
    }
    __syncthreads();

    const f32x4 zero4 = {0.f, 0.f, 0.f, 0.f};
    f32x4 acc[2][4];
    #pragma unroll
    for (int mt = 0; mt < 2; ++mt)
        #pragma unroll
        for (int nt = 0; nt < 4; ++nt) acc[mt][nt] = zero4;

    const __bf16* wrow0 = W1 + (size_t)(wv * 32 + lr) * 256 + g * 8;
    const __bf16* wrow1 = wrow0 + 16 * 256;

    #pragma unroll
    for (int kt = 0; kt < 8; ++kt) {
        bf16x8 a0 = *(const bf16x8*)(wrow0 + kt * 32);
        bf16x8 a1 = *(const bf16x8*)(wrow1 + kt * 32);
        #pragma unroll
        for (int nt = 0; nt < 4; ++nt) {
            const char* xrow = (const char*)&Xl[(nt * 16 + lr) * 256];
            bf16x8 bfr = *(const bf16x8*)(xrow + (((kt * 32 + g * 8) * 2) ^ sw));
            acc[0][nt] = __builtin_amdgcn_mfma_f32_16x16x32_bf16(a0, bfr, acc[0][nt], 0, 0, 0);
            acc[1][nt] = __builtin_amdgcn_mfma_f32_16x16x32_bf16(a1, bfr, acc[1][nt], 0, 0, 0);
        }
    }

    float4 bia[2];
    bia[0] = *(const float4*)&bias1[b * 128 + wv * 32 + g * 4];
    bia[1] = *(const float4*)&bias1[b * 128 + wv * 32 + 16 + g * 4];
    __syncthreads();   // Xl reads done before it gets aliased later
    #pragma unroll
    for (int mt = 0; mt < 2; ++mt) {
        #pragma unroll
        for (int nt = 0; nt < 4; ++nt) {
            const int p = nt * 16 + lr;
            char* trow = (char*)&Tl[p * 128];
            const int ob = (wv * 32 + mt * 16 + g * 4) * 2;
            bf16x4 tv;
            tv[0] = (__bf16)fmaxf(acc[mt][nt][0] + bia[mt].x, 0.f);
            tv[1] = (__bf16)fmaxf(acc[mt][nt][1] + bia[mt].y, 0.f);
            tv[2] = (__bf16)fmaxf(acc[mt][nt][2] + bia[mt].z, 0.f);
            tv[3] = (__bf16)fmaxf(acc[mt][nt][3] + bia[mt].w, 0.f);
            *(bf16x4*)(trow + (ob ^ sw)) = tv;
        }
    }
    __syncthreads();

    f32x4 acc2[2];
    acc2[0] = zero4; acc2[1] = zero4;
    const int p = wv * 16 + lr;
    const char* trow = (const char*)&Tl[p * 128];
    const __bf16* w2r0 = W2 + (size_t)lr * 128 + g * 8;
    const __bf16* w2r1 = w2r0 + 16 * 128;
    #pragma unroll
    for (int kt = 0; kt < 4; ++kt) {
        bf16x8 bfr = *(const bf16x8*)(trow + (((kt * 32 + g * 8) * 2) ^ sw));
        bf16x8 a0 = *(const bf16x8*)(w2r0 + kt * 32);
        bf16x8 a1 = *(const bf16x8*)(w2r1 + kt * 32);
        acc2[0] = __builtin_amdgcn_mfma_f32_16x16x32_bf16(a0, bfr, acc2[0], 0, 0, 0);
        acc2[1] = __builtin_amdgcn_mfma_f32_16x16x32_bf16(a1, bfr, acc2[1], 0, 0, 0);
    }
    float4 bb0 = *(const float4*)&b2[g * 4];
    float4 bb1 = *(const float4*)&b2[16 + g * 4];
    const int o0 = g * 4;

    // fused partial gram: tile [32 o][64 p] -> gt in LDS (stride 65)
    float* gt = (float*)Xl;
    gt[(o0 + 0) * 65 + p] = acc2[0][0] + bb0.x;
    gt[(o0 + 1) * 65 + p] = acc2[0][1] + bb0.y;
    gt[(o0 + 2) * 65 + p] = acc2[0][2] + bb0.z;
    gt[(o0 + 3) * 65 + p] = acc2[0][3] + bb0.w;
    gt[(16 + o0 + 0) * 65 + p] = acc2[1][0] + bb1.x;
    gt[(16 + o0 + 1) * 65 + p] = acc2[1][1] + bb1.y;
    gt[(16 + o0 + 2) * 65 + p] = acc2[1][2] + bb1.z;
    gt[(16 + o0 + 3) * 65 + p] = acc2[1][3] + bb1.w;
    __syncthreads();
    const int gi = tid >> 3, jb = (tid & 7) * 4;
    float g4[4] = {0.f, 0.f, 0.f, 0.f};
    #pragma unroll 8
    for (int n = 0; n < 64; ++n) {
        float si = gt[gi * 65 + n];
        #pragma unroll
        for (int q = 0; q < 4; ++q)
            g4[q] = fmaf(si, gt[(jb + q) * 65 + n], g4[q]);
    }
    float* dst = partial + ((size_t)(b * 256 + blockIdx.x)) * 1024 + tid * 4;
    #pragma unroll
    for (int q = 0; q < 4; ++q) dst[q] = g4[q];
}

// ---------------- Kernel 3: reduce 256 partials + softmax + scale ----------
__global__ __launch_bounds__(1024) void k_softmax2(const float* __restrict__ partial,
                                                   float* __restrict__ scov) {
    int b = blockIdx.x;
    int j = threadIdx.x, i = threadIdx.y;
    const float* base = partial + (size_t)b * 256 * 1024 + i * 32 + j;
    float v0 = 0.f, v1 = 0.f, v2 = 0.f, v3 = 0.f;
    #pragma unroll 4
    for (int s = 0; s < 256; s += 4) {
        v0 += base[(s + 0) * 1024];
        v1 += base[(s + 1) * 1024];
        v2 += base[(s + 2) * 1024];
        v3 += base[(s + 3) * 1024];
    }
    float v = ((v0 + v1) + (v2 + v3)) * (1.f / (float)HW);
    float m = v;
    #pragma unroll
    for (int d = 16; d > 0; d >>= 1) m = fmaxf(m, __shfl_xor(m, d, 32));
    float e = expf(v - m);
    float sum = e;
    #pragma unroll
    for (int d = 16; d > 0; d >>= 1) sum += __shfl_xor(sum, d, 32);
    scov[(size_t)b * 1024 + i * 32 + j] = e / sum * 0.17677669529663687f;
}

// ---------------- Kernel 4: FUSED net(content) + g=scov@cF + up-conv + out --
// EXACT r14 structure; single change: out stores are REGULAR (allocating),
// not NT — testing the NT-store drain-rate hypothesis (fill kernels hit
// 7 TB/s with allocating stores; our NT-store kernels cap at ~2.4 TB/s).
__global__ __launch_bounds__(256) void k_netc_final(const __bf16* __restrict__ x,
                                                    const __bf16* __restrict__ W1,
                                                    const float* __restrict__ bias1,
                                                    const __bf16* __restrict__ W2,
                                                    const float* __restrict__ b2,
                                                    const float* __restrict__ scov,
                                                    const float* __restrict__ wu,
                                                    const float* __restrict__ bu,
                                                    const float* __restrict__ smean,
                                                    float* __restrict__ out) {
    __shared__ __bf16 Xl[64 * 256];   // 32 KB, lives whole kernel (residual source)
    __shared__ __bf16 Tl[64 * 128];   // 16 KB; aliased as sC f32[32][64] after conv2
    __shared__ float sCov[1024];      // 4 KB
    __shared__ float sG[32 * 64];     // 8 KB
    const int tid = threadIdx.x;
    const int l = tid & 63, wv = tid >> 6;
    const int lr = l & 15, g = l >> 4;
    const int sw = (lr & 7) << 4;
    const int p0 = blockIdx.x * 64;
    const int b = blockIdx.y;
    const __bf16* xb = x + (size_t)b * C_IN * HW;

    #pragma unroll
    for (int q = 0; q < 4; ++q)
        sCov[tid + 256 * q] = scov[(size_t)b * 1024 + tid + 256 * q];
    {
        const int p = wv * 16 + lr;
        const __bf16* xp = xb + p0 + p;
        char* row = (char*)&Xl[p * 256];
        #pragma unroll 4
        for (int cc = 0; cc < 16; ++cc) {
            const int c = cc * 16 + g * 4;
            bf16x4 v;
            v[0] = xp[(size_t)(c + 0) * HW];
            v[1] = xp[(size_t)(c + 1) * HW];
            v[2] = xp[(size_t)(c + 2) * HW];
            v[3] = xp[(size_t)(c + 3) * HW];
            *(bf16x4*)(row + ((c * 2) ^ sw)) = v;
        }
    }
    __syncthreads();

    const f32x4 zero4 = {0.f, 0.f, 0.f, 0.f};
    f32x4 acc1[2][4];
    #pragma unroll
    for (int mt = 0; mt < 2; ++mt)
        #pragma unroll
        for (int nt = 0; nt < 4; ++nt) acc1[mt][nt] = zero4;

    const __bf16* W1b = W1 + ((size_t)b << 15);
    const __bf16* wrow0 = W1b + (size_t)(wv * 32 + lr) * 256 + g * 8;
    const __bf16* wrow1 = wrow0 + 16 * 256;

    #pragma unroll
    for (int kt = 0; kt < 8; ++kt) {
        bf16x8 a0 = *(const bf16x8*)(wrow0 + kt * 32);
        bf16x8 a1 = *(const bf16x8*)(wrow1 + kt * 32);
        #pragma unroll
        for (int nt = 0; nt < 4; ++nt) {
            const char* xrow = (const char*)&Xl[(nt * 16 + lr) * 256];
            bf16x8 bfr = *(const bf16x8*)(xrow + (((kt * 32 + g * 8) * 2) ^ sw));
            acc1[0][nt] = __builtin_amdgcn_mfma_f32_16x16x32_bf16(a0, bfr, acc1[0][nt], 0, 0, 0);
            acc1[1][nt] = __builtin_amdgcn_mfma_f32_16x16x32_bf16(a1, bfr, acc1[1][nt], 0, 0, 0);
        }
    }

    float4 bia[2];
    bia[0] = *(const float4*)&bias1[b * 128 + wv * 32 + g * 4];
    bia[1] = *(const float4*)&bias1[b * 128 + wv * 32 + 16 + g * 4];
    #pragma unroll
    for (int mt = 0; mt < 2; ++mt) {
        #pragma unroll
        for (int nt = 0; nt < 4; ++nt) {
            const int p = nt * 16 + lr;
            char* trow = (char*)&Tl[p * 128];
            const int ob = (wv * 32 + mt * 16 + g * 4) * 2;
            bf16x4 tv;
            tv[0] = (__bf16)fmaxf(acc1[mt][nt][0] + bia[mt].x, 0.f);
            tv[1] = (__bf16)fmaxf(acc1[mt][nt][1] + bia[mt].y, 0.f);
            tv[2] = (__bf16)fmaxf(acc1[mt][nt][2] + bia[mt].z, 0.f);
            tv[3] = (__bf16)fmaxf(acc1[mt][nt][3] + bia[mt].w, 0.f);
            *(bf16x4*)(trow + (ob ^ sw)) = tv;
        }
    }
    __syncthreads();

    f32x4 acc2[2];
    acc2[0] = zero4; acc2[1] = zero4;
    const int p = wv * 16 + lr;
    {
        const char* trow = (const char*)&Tl[p * 128];
        const __bf16* w2r0 = W2 + (size_t)lr * 128 + g * 8;
        const __bf16* w2r1 = w2r0 + 16 * 128;
        #pragma unroll
        for (int kt = 0; kt < 4; ++kt) {
            bf16x8 bfr = *(const bf16x8*)(trow + (((kt * 32 + g * 8) * 2) ^ sw));
            bf16x8 a0 = *(const bf16x8*)(w2r0 + kt * 32);
            bf16x8 a1 = *(const bf16x8*)(w2r1 + kt * 32);
            acc2[0] = __builtin_amdgcn_mfma_f32_16x16x32_bf16(a0, bfr, acc2[0], 0, 0, 0);
            acc2[1] = __builtin_amdgcn_mfma_f32_16x16x32_bf16(a1, bfr, acc2[1], 0, 0, 0);
        }
    }
    float4 bb0 = *(const float4*)&b2[g * 4];
    float4 bb1 = *(const float4*)&b2[16 + g * 4];
    const int o0 = g * 4;

    __syncthreads();                 // all Tl reads done; alias as sC f32[32][64]
    float* sC = (float*)Tl;
    sC[(o0 + 0) * 64 + p] = acc2[0][0] + bb0.x;
    sC[(o0 + 1) * 64 + p] = acc2[0][1] + bb0.y;
    sC[(o0 + 2) * 64 + p] = acc2[0][2] + bb0.z;
    sC[(o0 + 3) * 64 + p] = acc2[0][3] + bb0.w;
    sC[(16 + o0 + 0) * 64 + p] = acc2[1][0] + bb1.x;
    sC[(16 + o0 + 1) * 64 + p] = acc2[1][1] + bb1.y;
    sC[(16 + o0 + 2) * 64 + p] = acc2[1][2] + bb1.z;
    sC[(16 + o0 + 3) * 64 + p] = acc2[1][3] + bb1.w;
    __syncthreads();

    {   // g = scov @ cF_tile
        int gp = tid & 63, gib = (tid >> 6) * 8;
        #pragma unroll
        for (int rr = 0; rr < 8; ++rr) {
            int gi = gib + rr;
            float a = 0.f;
            #pragma unroll
            for (int k = 0; k < 32; ++k)
                a = fmaf(sCov[gi * 32 + k], sC[k * 64 + gp], a);
            sG[gi * 64 + gp] = a;
        }
    }
    __syncthreads();

    // out = wu@g + bu + smean + residual (from Xl)
    const int tx = tid & 7, ty = tid >> 3;
    const float* wurow = wu + (size_t)(ty * 8) * 32;   // 32 KB table via L1
    float acc[8][8];
    #pragma unroll
    for (int i = 0; i < 8; ++i)
        #pragma unroll
        for (int j = 0; j < 8; ++j) acc[i][j] = 0.f;
    #pragma unroll 4
    for (int k = 0; k < 32; ++k) {
        float a[8];
        #pragma unroll
        for (int i = 0; i < 8; ++i) a[i] = wurow[i * 32 + k];
        float4 b4a = *(const float4*)&sG[k * 64 + tx * 8];
        float4 b4b = *(const float4*)&sG[k * 64 + tx * 8 + 4];
        float bb[8] = {b4a.x, b4a.y, b4a.z, b4a.w, b4b.x, b4b.y, b4b.z, b4b.w};
        #pragma unroll
        for (int i = 0; i < 8; ++i)
            #pragma unroll
            for (int j = 0; j < 8; ++j)
                acc[i][j] = fmaf(a[i], bb[j], acc[i][j]);
    }
    float cvv[8][8];
    #pragma unroll
    for (int j = 0; j < 8; ++j) {
        const int pl = tx * 8 + j;
        bf16x8 rv = *(const bf16x8*)((const char*)Xl + pl * 512 + ((ty * 16) ^ (j << 4)));
        #pragma unroll
        for (int i = 0; i < 8; ++i) cvv[i][j] = (float)rv[i];
    }
    #pragma unroll
    for (int i = 0; i < 8; ++i) {
        int o = ty * 8 + i;
        float add = bu[o] + smean[b * 256 + o];
        float* dst = out + (size_t)b * C_IN * HW + (size_t)o * HW + p0 + tx * 8;
        f32x4 r0 = {acc[i][0] + add + cvv[i][0], acc[i][1] + add + cvv[i][1],
                    acc[i][2] + add + cvv[i][2], acc[i][3] + add + cvv[i][3]};
        f32x4 r1 = {acc[i][4] + add + cvv[i][4], acc[i][5] + add + cvv[i][5],
                    acc[i][6] + add + cvv[i][6], acc[i][7] + add + cvv[i][7]};
        *(f32x4*)dst = r0;           // regular (allocating) stores — the A/B change
        *(f32x4*)(dst + 4) = r1;
    }
}

extern "C" void kernel_launch(void* const* d_in, const int* in_sizes, int n_in,
                              void* d_out, int out_size, void* d_ws, size_t ws_size,
                              hipStream_t stream) {
    const float* content = (const float*)d_in[0];
    const float* style   = (const float*)d_in[1];
    const float* w1      = (const float*)d_in[2];
    const float* b1      = (const float*)d_in[3];
    const float* w2      = (const float*)d_in[4];
    const float* b2      = (const float*)d_in[5];
    const float* wu      = (const float*)d_in[6];
    const float* bu      = (const float*)d_in[7];
    float* out = (float*)d_out;
    float* ws  = (float*)d_ws;

    // layout (float offsets); total ~143 MB
    float* cmean   = ws;                       // 2048
    float* crstd   = ws + 2048;                // 2048
    float* smean   = ws + 4096;                // 2048
    float* scov    = ws + 6144;                // 8192
    float* bias1c  = ws + 14336;               // 1024
    float* bias1s  = ws + 15360;               // 1024
    __bf16* W2b    = (__bf16*)(ws + 16384);    // 4096 bf16
    __bf16* W1s    = (__bf16*)(ws + 18432);    // 32768 bf16
    __bf16* W1c    = (__bf16*)(ws + 34816);    // 262144 bf16
    float* partial = ws + 165888;              // 2097152 (8 MB)
    __bf16* cbf    = (__bf16*)(ws + 2263040);  // 33554432 bf16 (67 MB)
    __bf16* sbf    = (__bf16*)(ws + 19040256); // 33554432 bf16 (67 MB)

    k_stats10<<<dim3(2048), 512, 0, stream>>>(content, style, cmean, crstd, smean, cbf, sbf);
    k_wprep2<<<dim3(128, 8), 256, 0, stream>>>(w1, b1, w2, cmean, crstd, smean,
                                               W1c, bias1c, W1s, bias1s, W2b);
    k_net_s<<<dim3(256, 8), 256, 0, stream>>>(sbf, W1s, bias1s, W2b, b2, partial);
    k_softmax2<<<dim3(8), dim3(32, 32), 0, stream>>>(partial, scov);
    k_netc_final<<<dim3(256, 8), 256, 0, stream>>>(cbf, W1c, bias1c, W2b, b2,
                                                   scov, wu, bu, smean, out);
}

// Round 21
// 214.284 us; speedup vs baseline: 1.1162x; 1.0362x over previous
//
#include <hip/hip_runtime.h>

#define HW 16384
#define C_IN 256
#define C_MID 128
#define C_OUT 32
#define EPSF 1e-5f

typedef __bf16 bf16x8 __attribute__((ext_vector_type(8)));
typedef __bf16 bf16x4 __attribute__((ext_vector_type(4)));
typedef float f32x4 __attribute__((ext_vector_type(4)));

__device__ __forceinline__ bf16x4 cvt4(f32x4 v) {
    bf16x4 r;
    r[0] = (__bf16)v[0]; r[1] = (__bf16)v[1];
    r[2] = (__bf16)v[2]; r[3] = (__bf16)v[3];
    return r;
}

// ---------------- Kernel 1: stats + bf16 copies of both inputs ----------
__global__ __launch_bounds__(512) void k_stats10(const float* __restrict__ content,
                                                 const float* __restrict__ style,
                                                 float* __restrict__ cmean,
                                                 float* __restrict__ crstd,
                                                 float* __restrict__ smean,
                                                 __bf16* __restrict__ cbf,
                                                 __bf16* __restrict__ sbf) {
    const int bc = blockIdx.x;          // 0..2047
    const int t = threadIdx.x;          // 0..511
    const f32x4* cp = (const f32x4*)(content + (size_t)bc * HW);
    const f32x4* sp = (const f32x4*)(style + (size_t)bc * HW);
    const int phase = (bc * 257) & 4095;

    int idx[8];
    #pragma unroll
    for (int i = 0; i < 8; ++i) idx[i] = (phase + t + i * 512) & 4095;

    f32x4 c[8], s[8];
    #pragma unroll
    for (int i = 0; i < 8; ++i) c[i] = __builtin_nontemporal_load(cp + idx[i]);
    #pragma unroll
    for (int i = 0; i < 8; ++i) s[i] = __builtin_nontemporal_load(sp + idx[i]);
    asm volatile("" ::
        "v"(c[0]), "v"(c[1]), "v"(c[2]), "v"(c[3]), "v"(c[4]), "v"(c[5]), "v"(c[6]), "v"(c[7]),
        "v"(s[0]), "v"(s[1]), "v"(s[2]), "v"(s[3]), "v"(s[4]), "v"(s[5]), "v"(s[6]), "v"(s[7]));

    {
        bf16x4* cb = (bf16x4*)(cbf + (size_t)bc * HW);
        bf16x4* sb = (bf16x4*)(sbf + (size_t)bc * HW);
        #pragma unroll
        for (int i = 0; i < 8; ++i) {
            cb[idx[i]] = cvt4(c[i]);
            sb[idx[i]] = cvt4(s[i]);
        }
    }

    float cs, cq, ss;
    {
        f32x4 a01 = c[0] + c[1], a23 = c[2] + c[3], a45 = c[4] + c[5], a67 = c[6] + c[7];
        f32x4 a = (a01 + a23) + (a45 + a67);
        cs = (a[0] + a[1]) + (a[2] + a[3]);
        f32x4 q01 = c[0]*c[0] + c[1]*c[1], q23 = c[2]*c[2] + c[3]*c[3];
        f32x4 q45 = c[4]*c[4] + c[5]*c[5], q67 = c[6]*c[6] + c[7]*c[7];
        f32x4 q = (q01 + q23) + (q45 + q67);
        cq = (q[0] + q[1]) + (q[2] + q[3]);
        f32x4 b01 = s[0] + s[1], b23 = s[2] + s[3], b45 = s[4] + s[5], b67 = s[6] + s[7];
        f32x4 bsum = (b01 + b23) + (b45 + b67);
        ss = (bsum[0] + bsum[1]) + (bsum[2] + bsum[3]);
    }

    #pragma unroll
    for (int d = 32; d > 0; d >>= 1) {
        cs += __shfl_xor(cs, d, 64);
        cq += __shfl_xor(cq, d, 64);
        ss += __shfl_xor(ss, d, 64);
    }
    __shared__ float rs[8], rq[8], rss[8];
    const int wv = t >> 6;
    if ((t & 63) == 0) { rs[wv] = cs; rq[wv] = cq; rss[wv] = ss; }
    __syncthreads();
    if (t == 0) {
        float S = 0.f, Q = 0.f, SS = 0.f;
        #pragma unroll
        for (int i = 0; i < 8; ++i) { S += rs[i]; Q += rq[i]; SS += rss[i]; }
        float n = (float)HW;
        float var = (Q - S * S / n) / (n - 1.f);
        cmean[bc] = S / n;
        crstd[bc] = 1.f / sqrtf(var + EPSF);
        smean[bc] = SS / n;
    }
}

// ---------------- Prep: fold norm into conv1 weights + w2 convert ----------
__global__ __launch_bounds__(256) void k_wprep2(const float* __restrict__ w1,
                                                const float* __restrict__ b1,
                                                const float* __restrict__ w2,
                                                const float* __restrict__ cmean,
                                                const float* __restrict__ crstd,
                                                const float* __restrict__ smean,
                                                __bf16* __restrict__ W1c,
                                                float* __restrict__ bias1c,
                                                __bf16* __restrict__ W1s,
                                                float* __restrict__ bias1s,
                                                __bf16* __restrict__ W2b) {
    int o = blockIdx.x, b = blockIdx.y, t = threadIdx.x;
    float w = w1[o * 256 + t];
    float r = crstd[b * 256 + t];
    float wc = w * r;
    W1c[((size_t)(b * 128 + o)) * 256 + t] = (__bf16)wc;
    if (b == 0) {
        W1s[o * 256 + t] = (__bf16)w;
        if (t < 32) W2b[o * 32 + t] = (__bf16)w2[o * 32 + t];
    }
    float pc = wc * cmean[b * 256 + t];
    float ps = w * smean[b * 256 + t];
    __shared__ float rA[256], rB[256];
    rA[t] = pc; rB[t] = ps;
    __syncthreads();
    for (int off = 128; off > 0; off >>= 1) {
        if (t < off) { rA[t] += rA[t + off]; rB[t] += rB[t + off]; }
        __syncthreads();
    }
    if (t == 0) {
        bias1c[b * 128 + o] = b1[o] - rA[0];
        bias1s[b * 128 + o] = b1[o] - rB[0];
    }
}

// ---------------- Kernel 2: MFMA fused net (style) + partial gram ----------
__global__ __launch_bounds__(256) void k_net_s(const __bf16* __restrict__ x,
                                               const __bf16* __restrict__ W1,
                                               const float* __restrict__ bias1,
                                               const __bf16* __restrict__ W2,
                                               const float* __restrict__ b2,
                                               float* __restrict__ partial) {
    __shared__ __bf16 Xl[64 * 256];   // 32 KB; reused as f32 gram tile at end
    __shared__ __bf16 Tl[64 * 128];   // 16 KB
    const int tid = threadIdx.x;
    const int l = tid & 63, wv = tid >> 6;
    const int lr = l & 15, g = l >> 4;
    const int sw = (lr & 7) << 4;
    const int p0 = blockIdx.x * 64;
    const int b = blockIdx.y;
    const __bf16* xb = x + (size_t)b * C_IN * HW;

    {
        const int p = wv * 16 + lr;
        const __bf16* xp = xb + p0 + p;
        char* row = (char*)&Xl[p * 256];
        #pragma unroll 4
        for (int cc = 0; cc < 16; ++cc) {
            const int c = cc * 16 + g * 4;
            bf16x4 v;
            v[0] = xp[(size_t)(c + 0) * HW];
            v[1] = xp[(size_t)(c + 1) * HW];
            v[2] = xp[(size_t)(c + 2) * HW];
            v[3] = xp[(size_t)(c + 3) * HW];
            *(bf16x4*)(row + ((c * 2) ^ sw)) = v;
        }
    }
    __syncthreads();

    const f32x4 zero4 = {0.f, 0.f, 0.f, 0.f};
    f32x4 acc[2][4];
    #pragma unroll
    for (int mt = 0; mt < 2; ++mt)
        #pragma unroll
        for (int nt = 0; nt < 4; ++nt) acc[mt][nt] = zero4;

    const __bf16* wrow0 = W1 + (size_t)(wv * 32 + lr) * 256 + g * 8;
    const __bf16* wrow1 = wrow0 + 16 * 256;

    #pragma unroll
    for (int kt = 0; kt < 8; ++kt) {
        bf16x8 a0 = *(const bf16x8*)(wrow0 + kt * 32);
        bf16x8 a1 = *(const bf16x8*)(wrow1 + kt * 32);
        #pragma unroll
        for (int nt = 0; nt < 4; ++nt) {
            const char* xrow = (const char*)&Xl[(nt * 16 + lr) * 256];
            bf16x8 bfr = *(const bf16x8*)(xrow + (((kt * 32 + g * 8) * 2) ^ sw));
            acc[0][nt] = __builtin_amdgcn_mfma_f32_16x16x32_bf16(a0, bfr, acc[0][nt], 0, 0, 0);
            acc[1][nt] = __builtin_amdgcn_mfma_f32_16x16x32_bf16(a1, bfr, acc[1][nt], 0, 0, 0);
        }
    }

    float4 bia[2];
    bia[0] = *(const float4*)&bias1[b * 128 + wv * 32 + g * 4];
    bia[1] = *(const float4*)&bias1[b * 128 + wv * 32 + 16 + g * 4];
    __syncthreads();   // Xl reads done before it gets aliased later
    #pragma unroll
    for (int mt = 0; mt < 2; ++mt) {
        #pragma unroll
        for (int nt = 0; nt < 4; ++nt) {
            const int p = nt * 16 + lr;
            char* trow = (char*)&Tl[p * 128];
            const int ob = (wv * 32 + mt * 16 + g * 4) * 2;
            bf16x4 tv;
            tv[0] = (__bf16)fmaxf(acc[mt][nt][0] + bia[mt].x, 0.f);
            tv[1] = (__bf16)fmaxf(acc[mt][nt][1] + bia[mt].y, 0.f);
            tv[2] = (__bf16)fmaxf(acc[mt][nt][2] + bia[mt].z, 0.f);
            tv[3] = (__bf16)fmaxf(acc[mt][nt][3] + bia[mt].w, 0.f);
            *(bf16x4*)(trow + (ob ^ sw)) = tv;
        }
    }
    __syncthreads();

    f32x4 acc2[2];
    acc2[0] = zero4; acc2[1] = zero4;
    const int p = wv * 16 + lr;
    const char* trow = (const char*)&Tl[p * 128];
    const __bf16* w2r0 = W2 + (size_t)lr * 128 + g * 8;
    const __bf16* w2r1 = w2r0 + 16 * 128;
    #pragma unroll
    for (int kt = 0; kt < 4; ++kt) {
        bf16x8 bfr = *(const bf16x8*)(trow + (((kt * 32 + g * 8) * 2) ^ sw));
        bf16x8 a0 = *(const bf16x8*)(w2r0 + kt * 32);
        bf16x8 a1 = *(const bf16x8*)(w2r1 + kt * 32);
        acc2[0] = __builtin_amdgcn_mfma_f32_16x16x32_bf16(a0, bfr, acc2[0], 0, 0, 0);
        acc2[1] = __builtin_amdgcn_mfma_f32_16x16x32_bf16(a1, bfr, acc2[1], 0, 0, 0);
    }
    float4 bb0 = *(const float4*)&b2[g * 4];
    float4 bb1 = *(const float4*)&b2[16 + g * 4];
    const int o0 = g * 4;

    // fused partial gram: tile [32 o][64 p] -> gt in LDS (stride 65)
    float* gt = (float*)Xl;
    gt[(o0 + 0) * 65 + p] = acc2[0][0] + bb0.x;
    gt[(o0 + 1) * 65 + p] = acc2[0][1] + bb0.y;
    gt[(o0 + 2) * 65 + p] = acc2[0][2] + bb0.z;
    gt[(o0 + 3) * 65 + p] = acc2[0][3] + bb0.w;
    gt[(16 + o0 + 0) * 65 + p] = acc2[1][0] + bb1.x;
    gt[(16 + o0 + 1) * 65 + p] = acc2[1][1] + bb1.y;
    gt[(16 + o0 + 2) * 65 + p] = acc2[1][2] + bb1.z;
    gt[(16 + o0 + 3) * 65 + p] = acc2[1][3] + bb1.w;
    __syncthreads();
    const int gi = tid >> 3, jb = (tid & 7) * 4;
    float g4[4] = {0.f, 0.f, 0.f, 0.f};
    #pragma unroll 8
    for (int n = 0; n < 64; ++n) {
        float si = gt[gi * 65 + n];
        #pragma unroll
        for (int q = 0; q < 4; ++q)
            g4[q] = fmaf(si, gt[(jb + q) * 65 + n], g4[q]);
    }
    float* dst = partial + ((size_t)(b * 256 + blockIdx.x)) * 1024 + tid * 4;
    #pragma unroll
    for (int q = 0; q < 4; ++q) dst[q] = g4[q];
}

// ---------------- Kernel 3: reduce 256 partials + softmax + scale ----------
__global__ __launch_bounds__(1024) void k_softmax2(const float* __restrict__ partial,
                                                   float* __restrict__ scov) {
    int b = blockIdx.x;
    int j = threadIdx.x, i = threadIdx.y;
    const float* base = partial + (size_t)b * 256 * 1024 + i * 32 + j;
    float v0 = 0.f, v1 = 0.f, v2 = 0.f, v3 = 0.f;
    #pragma unroll 4
    for (int s = 0; s < 256; s += 4) {
        v0 += base[(s + 0) * 1024];
        v1 += base[(s + 1) * 1024];
        v2 += base[(s + 2) * 1024];
        v3 += base[(s + 3) * 1024];
    }
    float v = ((v0 + v1) + (v2 + v3)) * (1.f / (float)HW);
    float m = v;
    #pragma unroll
    for (int d = 16; d > 0; d >>= 1) m = fmaxf(m, __shfl_xor(m, d, 32));
    float e = expf(v - m);
    float sum = e;
    #pragma unroll
    for (int d = 16; d > 0; d >>= 1) sum += __shfl_xor(sum, d, 32);
    scov[(size_t)b * 1024 + i * 32 + j] = e / sum * 0.17677669529663687f;
}

// ---------------- Kernel 4: FUSED net(content) + g=scov@cF + up-conv + out --
// 512-thread version (8 waves/block, 2 blocks/CU -> 16 waves/CU): each phase
// has 2x issue width / outstanding memory ops; 4 block generations not 8.
__global__ __launch_bounds__(512) void k_netc_final(const __bf16* __restrict__ x,
                                                    const __bf16* __restrict__ W1,
                                                    const float* __restrict__ bias1,
                                                    const __bf16* __restrict__ W2,
                                                    const float* __restrict__ b2,
                                                    const float* __restrict__ scov,
                                                    const float* __restrict__ wu,
                                                    const float* __restrict__ bu,
                                                    const float* __restrict__ smean,
                                                    float* __restrict__ out) {
    __shared__ __bf16 Xl[64 * 256];   // 32 KB, lives whole kernel (residual source)
    __shared__ __bf16 Tl[64 * 128];   // 16 KB; aliased as sC f32[32][64] after conv2
    __shared__ float sCov[1024];      // 4 KB
    __shared__ float sG[32 * 64];     // 8 KB
    const int tid = threadIdx.x;      // 0..511
    const int l = tid & 63, wv = tid >> 6;   // 8 waves
    const int lr = l & 15, g = l >> 4;
    const int sw = (lr & 7) << 4;
    const int p0 = blockIdx.x * 64;
    const int b = blockIdx.y;
    const __bf16* xb = x + (size_t)b * C_IN * HW;

    sCov[tid] = scov[(size_t)b * 1024 + tid];
    sCov[tid + 512] = scov[(size_t)b * 1024 + tid + 512];

    {   // stage: wave-pairs split channel range; p = (wv&3)*16+lr
        const int pp = (wv & 3) * 16 + lr;
        const __bf16* xp = xb + p0 + pp;
        char* row = (char*)&Xl[pp * 256];
        const int cc0 = (wv >> 2) * 8;
        #pragma unroll
        for (int cc = 0; cc < 8; ++cc) {
            const int c = (cc0 + cc) * 16 + g * 4;
            bf16x4 v;
            v[0] = xp[(size_t)(c + 0) * HW];
            v[1] = xp[(size_t)(c + 1) * HW];
            v[2] = xp[(size_t)(c + 2) * HW];
            v[3] = xp[(size_t)(c + 3) * HW];
            *(bf16x4*)(row + ((c * 2) ^ sw)) = v;
        }
    }
    __syncthreads();

    const f32x4 zero4 = {0.f, 0.f, 0.f, 0.f};
    // conv1: wave wv owns m-tile wv (16 outs), all 4 p-tiles
    f32x4 acc1[4];
    #pragma unroll
    for (int nt = 0; nt < 4; ++nt) acc1[nt] = zero4;

    const __bf16* W1b = W1 + ((size_t)b << 15);
    const __bf16* wrow = W1b + (size_t)(wv * 16 + lr) * 256 + g * 8;

    #pragma unroll
    for (int kt = 0; kt < 8; ++kt) {
        bf16x8 a0 = *(const bf16x8*)(wrow + kt * 32);
        #pragma unroll
        for (int nt = 0; nt < 4; ++nt) {
            const char* xrow = (const char*)&Xl[(nt * 16 + lr) * 256];
            bf16x8 bfr = *(const bf16x8*)(xrow + (((kt * 32 + g * 8) * 2) ^ sw));
            acc1[nt] = __builtin_amdgcn_mfma_f32_16x16x32_bf16(a0, bfr, acc1[nt], 0, 0, 0);
        }
    }

    float4 bia = *(const float4*)&bias1[b * 128 + wv * 16 + g * 4];
    #pragma unroll
    for (int nt = 0; nt < 4; ++nt) {
        const int p = nt * 16 + lr;
        char* trow = (char*)&Tl[p * 128];
        const int ob = (wv * 16 + g * 4) * 2;
        bf16x4 tv;
        tv[0] = (__bf16)fmaxf(acc1[nt][0] + bia.x, 0.f);
        tv[1] = (__bf16)fmaxf(acc1[nt][1] + bia.y, 0.f);
        tv[2] = (__bf16)fmaxf(acc1[nt][2] + bia.z, 0.f);
        tv[3] = (__bf16)fmaxf(acc1[nt][3] + bia.w, 0.f);
        *(bf16x4*)(trow + (ob ^ sw)) = tv;
    }
    __syncthreads();

    // conv2: wave -> (o2-half h = wv>>2, p-slice q = wv&3)
    f32x4 acc2 = zero4;
    const int p = (wv & 3) * 16 + lr;
    const int h = wv >> 2;
    {
        const char* trow = (const char*)&Tl[p * 128];
        const __bf16* w2r = W2 + (size_t)(h * 16 + lr) * 128 + g * 8;
        #pragma unroll
        for (int kt = 0; kt < 4; ++kt) {
            bf16x8 bfr = *(const bf16x8*)(trow + (((kt * 32 + g * 8) * 2) ^ sw));
            bf16x8 a0 = *(const bf16x8*)(w2r + kt * 32);
            acc2 = __builtin_amdgcn_mfma_f32_16x16x32_bf16(a0, bfr, acc2, 0, 0, 0);
        }
    }
    float4 bb = *(const float4*)&b2[h * 16 + g * 4];
    const int o0 = h * 16 + g * 4;

    __syncthreads();                 // all Tl reads done; alias as sC f32[32][64]
    float* sC = (float*)Tl;
    sC[(o0 + 0) * 64 + p] = acc2[0] + bb.x;
    sC[(o0 + 1) * 64 + p] = acc2[1] + bb.y;
    sC[(o0 + 2) * 64 + p] = acc2[2] + bb.z;
    sC[(o0 + 3) * 64 + p] = acc2[3] + bb.w;
    __syncthreads();

    {   // g = scov @ cF_tile : 512 threads, 4 rows each
        int gp = tid & 63, gib = (tid >> 6) * 4;
        #pragma unroll
        for (int rr = 0; rr < 4; ++rr) {
            int gi = gib + rr;
            float a = 0.f;
            #pragma unroll
            for (int k = 0; k < 32; ++k)
                a = fmaf(sCov[gi * 32 + k], sC[k * 64 + gp], a);
            sG[gi * 64 + gp] = a;
        }
    }
    __syncthreads();

    // out = wu@g + bu + smean + residual (from Xl); 4 o-rows x 8 p per thread
    const int tx = tid & 7, ty = tid >> 3;      // ty 0..63
    const float* wurow = wu + (size_t)(ty * 4) * 32;
    float acc[4][8];
    #pragma unroll
    for (int i = 0; i < 4; ++i)
        #pragma unroll
        for (int j = 0; j < 8; ++j) acc[i][j] = 0.f;
    #pragma unroll 4
    for (int k = 0; k < 32; ++k) {
        float a[4];
        #pragma unroll
        for (int i = 0; i < 4; ++i) a[i] = wurow[i * 32 + k];
        float4 b4a = *(const float4*)&sG[k * 64 + tx * 8];
        float4 b4b = *(const float4*)&sG[k * 64 + tx * 8 + 4];
        float bbv[8] = {b4a.x, b4a.y, b4a.z, b4a.w, b4b.x, b4b.y, b4b.z, b4b.w};
        #pragma unroll
        for (int i = 0; i < 4; ++i)
            #pragma unroll
            for (int j = 0; j < 8; ++j)
                acc[i][j] = fmaf(a[i], bbv[j], acc[i][j]);
    }
    float cvv[4][8];
    #pragma unroll
    for (int j = 0; j < 8; ++j) {
        const int pl = tx * 8 + j;
        // channels ty*4 .. ty*4+3 at byte (ty*8) ^ swizzle within row pl
        bf16x4 rv = *(const bf16x4*)((const char*)Xl + pl * 512 + ((ty * 8) ^ ((pl & 7) << 4)));
        #pragma unroll
        for (int i = 0; i < 4; ++i) cvv[i][j] = (float)rv[i];
    }
    #pragma unroll
    for (int i = 0; i < 4; ++i) {
        int o = ty * 4 + i;
        float add = bu[o] + smean[b * 256 + o];
        float* dst = out + (size_t)b * C_IN * HW + (size_t)o * HW + p0 + tx * 8;
        f32x4 r0 = {acc[i][0] + add + cvv[i][0], acc[i][1] + add + cvv[i][1],
                    acc[i][2] + add + cvv[i][2], acc[i][3] + add + cvv[i][3]};
        f32x4 r1 = {acc[i][4] + add + cvv[i][4], acc[i][5] + add + cvv[i][5],
                    acc[i][6] + add + cvv[i][6], acc[i][7] + add + cvv[i][7]};
        *(f32x4*)dst = r0;
        *(f32x4*)(dst + 4) = r1;
    }
}

extern "C" void kernel_launch(void* const* d_in, const int* in_sizes, int n_in,
                              void* d_out, int out_size, void* d_ws, size_t ws_size,
                              hipStream_t stream) {
    const float* content = (const float*)d_in[0];
    const float* style   = (const float*)d_in[1];
    const float* w1      = (const float*)d_in[2];
    const float* b1      = (const float*)d_in[3];
    const float* w2      = (const float*)d_in[4];
    const float* b2      = (const float*)d_in[5];
    const float* wu      = (const float*)d_in[6];
    const float* bu      = (const float*)d_in[7];
    float* out = (float*)d_out;
    float* ws  = (float*)d_ws;

    // layout (float offsets); total ~143 MB
    float* cmean   = ws;                       // 2048
    float* crstd   = ws + 2048;                // 2048
    float* smean   = ws + 4096;                // 2048
    float* scov    = ws + 6144;                // 8192
    float* bias1c  = ws + 14336;               // 1024
    float* bias1s  = ws + 15360;               // 1024
    __bf16* W2b    = (__bf16*)(ws + 16384);    // 4096 bf16
    __bf16* W1s    = (__bf16*)(ws + 18432);    // 32768 bf16
    __bf16* W1c    = (__bf16*)(ws + 34816);    // 262144 bf16
    float* partial = ws + 165888;              // 2097152 (8 MB)
    __bf16* cbf    = (__bf16*)(ws + 2263040);  // 33554432 bf16 (67 MB)
    __bf16* sbf    = (__bf16*)(ws + 19040256); // 33554432 bf16 (67 MB)

    k_stats10<<<dim3(2048), 512, 0, stream>>>(content, style, cmean, crstd, smean, cbf, sbf);
    k_wprep2<<<dim3(128, 8), 256, 0, stream>>>(w1, b1, w2, cmean, crstd, smean,
                                               W1c, bias1c, W1s, bias1s, W2b);
    k_net_s<<<dim3(256, 8), 256, 0, stream>>>(sbf, W1s, bias1s, W2b, b2, partial);
    k_softmax2<<<dim3(8), dim3(32, 32), 0, stream>>>(partial, scov);
    k_netc_final<<<dim3(256, 8), 512, 0, stream>>>(cbf, W1c, bias1c, W2b, b2,
                                                   scov, wu, bu, smean, out);
}